// Round 5
// baseline (231.859 us; speedup 1.0000x reference)
//
#include <hip/hip_runtime.h>
#include <hip/hip_cooperative_groups.h>
#include <float.h>

namespace cg = cooperative_groups;

#define Bsz 2048
#define Nn  1024
#define Dd  256

typedef __attribute__((ext_vector_type(8))) short bf16x8;
typedef __attribute__((ext_vector_type(4))) float f32x4;
typedef unsigned long long u64;

// round-to-nearest-even f32 -> bf16 bits
__device__ __forceinline__ unsigned short bfr(float x) {
    unsigned u = __float_as_uint(x);
    u += 0x7fffu + ((u >> 16) & 1u);
    return (unsigned short)(u >> 16);
}
__device__ __forceinline__ float bf2f(unsigned short h) {
    return __uint_as_float(((unsigned)h) << 16);
}

__device__ __forceinline__ void som_params(const int* __restrict__ step,
                                           const int* __restrict__ total,
                                           float* taxa, float* inv2s2) {
    float frac = (float)(*step) / (float)(*total);
    float e = __expf(-frac);
    *taxa = 0.5f * e;
    float sigma = 16.0f * e;              // SIGMA_INICIAL = 16
    *inv2s2 = 1.0f / (2.0f * sigma * sigma);
}

// sortable-u32 encoding of f32 (monotone), packed with index; min => argmin
// with first-index (lowest n) tie-break, matching jnp.argmin.
__device__ __forceinline__ u64 packsc(float f, int n) {
    unsigned u = __float_as_uint(f);
    u = (u & 0x80000000u) ? ~u : (u | 0x80000000u);
    return ((u64)u << 32) | (unsigned)n;
}

// ---------------------------------------------------------------------------
// ONE cooperative kernel: prep -> sync -> bmu -> sync -> hgen -> sync -> acc
// 512 blocks x 256 threads, 2 blocks/CU co-resident.
// ---------------------------------------------------------------------------
__global__ __launch_bounds__(256, 2) void fused_som(
    const float* __restrict__ X, const float* __restrict__ W,
    const int* __restrict__ step, const int* __restrict__ total,
    float* __restrict__ out, float* __restrict__ w2,
    u64* __restrict__ bmin, float* __restrict__ hsum,
    ushort* __restrict__ Xt, ushort* __restrict__ Xhi,
    ushort* __restrict__ Xlo, ushort* __restrict__ Whi,
    ushort* __restrict__ Wlo, ushort* __restrict__ Ht)
{
    cg::grid_group grid = cg::this_grid();
    const int bid = blockIdx.x;
    const int t   = threadIdx.x;
    const int w   = t >> 6, l = t & 63;
    const int lr  = l & 15, lg = l >> 4;

    __shared__ float lds_t[64][65];     // P0 transpose staging
    __shared__ float red[4][32][20];    // P3 cross-wave reduce (+4 pad)
    __shared__ float hws[4];            // P2 hsum partials

    // ================= P0: prep =================
    if (bid < 256) {
        // W: hi/lo split + w2.  4 rows/block, one wave per row.
        int row = bid * 4 + w;
        float4 v = ((const float4*)(W + (size_t)row * Dd))[l];
        float s = v.x*v.x + v.y*v.y + v.z*v.z + v.w*v.w;
        #pragma unroll
        for (int m = 32; m; m >>= 1) s += __shfl_xor(s, m, 64);
        if (l == 0) w2[row] = s;
        ushort4 h4, l4;
        h4.x = bfr(v.x); l4.x = bfr(v.x - bf2f(h4.x));
        h4.y = bfr(v.y); l4.y = bfr(v.y - bf2f(h4.y));
        h4.z = bfr(v.z); l4.z = bfr(v.z - bf2f(h4.z));
        h4.w = bfr(v.w); l4.w = bfr(v.w - bf2f(h4.w));
        *(ushort4*)&Whi[(size_t)row * Dd + l * 4] = h4;
        *(ushort4*)&Wlo[(size_t)row * Dd + l * 4] = l4;
    } else if (bid < 384) {
        // X: hi/lo split + bf16 transpose tile (64b x 64d)
        int idx = bid - 256;
        int b0 = (idx & 31) * 64;
        int d0 = (idx >> 5) * 64;
        #pragma unroll
        for (int p = 0; p < 4; ++p) {
            int flat = p * 256 + t;
            int row = flat >> 4, c4 = flat & 15;
            float4 v = *(const float4*)&X[(size_t)(b0 + row) * Dd + d0 + c4 * 4];
            ushort4 h4, l4;
            h4.x = bfr(v.x); l4.x = bfr(v.x - bf2f(h4.x));
            h4.y = bfr(v.y); l4.y = bfr(v.y - bf2f(h4.y));
            h4.z = bfr(v.z); l4.z = bfr(v.z - bf2f(h4.z));
            h4.w = bfr(v.w); l4.w = bfr(v.w - bf2f(h4.w));
            size_t off = (size_t)(b0 + row) * Dd + d0 + c4 * 4;
            *(ushort4*)&Xhi[off] = h4;
            *(ushort4*)&Xlo[off] = l4;
            lds_t[row][c4*4+0] = v.x; lds_t[row][c4*4+1] = v.y;
            lds_t[row][c4*4+2] = v.z; lds_t[row][c4*4+3] = v.w;
        }
        __syncthreads();
        #pragma unroll
        for (int q = 0; q < 2; ++q) {
            int idx2 = q * 256 + t;
            int d  = idx2 >> 3;
            int bs = (idx2 & 7) * 8;
            bf16x8 o;
            #pragma unroll
            for (int j = 0; j < 8; ++j) o[j] = (short)bfr(lds_t[bs + j][d]);
            *(bf16x8*)&Xt[(size_t)(d0 + d) * Bsz + b0 + bs] = o;
        }
    } else if (bid < 392) {
        bmin[(bid - 384) * 256 + t] = ~0ull;
    }
    grid.sync();

    // ================= P1: BMU (hi/lo-split MFMA) =================
    // block tile 64b x 64n; wave w owns n-slice of 16. score = w2 - 2*dot.
    {
        const int b0 = (bid >> 4) * 64;
        const int n0 = (bid & 15) * 64 + w * 16;

        f32x4 acc[4];
        #pragma unroll
        for (int m = 0; m < 4; ++m) { f32x4 z = {0.f,0.f,0.f,0.f}; acc[m] = z; }

        for (int kd = 0; kd < Dd; kd += 32) {
            bf16x8 ah[4], al[4], bh, bl;
            #pragma unroll
            for (int m = 0; m < 4; ++m) {
                size_t off = (size_t)(b0 + m*16 + lr) * Dd + kd + lg*8;
                ah[m] = *(const bf16x8*)&Xhi[off];
                al[m] = *(const bf16x8*)&Xlo[off];
            }
            size_t offb = (size_t)(n0 + lr) * Dd + kd + lg*8;
            bh = *(const bf16x8*)&Whi[offb];
            bl = *(const bf16x8*)&Wlo[offb];
            #pragma unroll
            for (int m = 0; m < 4; ++m) {
                acc[m] = __builtin_amdgcn_mfma_f32_16x16x32_bf16(ah[m], bh, acc[m], 0, 0, 0);
                acc[m] = __builtin_amdgcn_mfma_f32_16x16x32_bf16(ah[m], bl, acc[m], 0, 0, 0);
                acc[m] = __builtin_amdgcn_mfma_f32_16x16x32_bf16(al[m], bh, acc[m], 0, 0, 0);
            }
        }

        const int nidx = n0 + lr;
        const float w2v = w2[nidx];
        #pragma unroll
        for (int m = 0; m < 4; ++m)
            #pragma unroll
            for (int r = 0; r < 4; ++r) {
                u64 pm = packsc(w2v - 2.f * acc[m][r], nidx);
                #pragma unroll
                for (int msk = 1; msk < 16; msk <<= 1) {
                    unsigned plo = (unsigned)pm, phi = (unsigned)(pm >> 32);
                    plo = __shfl_xor(plo, msk, 64);
                    phi = __shfl_xor(phi, msk, 64);
                    u64 o = ((u64)phi << 32) | plo;
                    if (o < pm) pm = o;
                }
                if (lr == 0) atomicMin(&bmin[b0 + m*16 + lg*4 + r], pm);
            }
    }
    grid.sync();

    // ================= P2: h generation + hsum =================
    // 2 n per block; Ht[n][b] bf16, hsum[n] exact f32.
    {
        float taxa, inv2s2;
        som_params(step, total, &taxa, &inv2s2);
        #pragma unroll
        for (int q = 0; q < 2; ++q) {
            const int n = bid * 2 + q;
            const int nx = n & 31, ny = n >> 5;
            float part = 0.f;
            bf16x8 o;
            #pragma unroll
            for (int j = 0; j < 8; ++j) {
                unsigned idx = (unsigned)(bmin[t*8 + j] & 0xffffffffu);
                int dx = nx - (int)(idx & 31);
                int dy = ny - (int)(idx >> 5);
                float h = __expf(-(float)(dx*dx + dy*dy) * inv2s2);
                o[j] = (short)bfr(h);
                part += h;
            }
            *(bf16x8*)&Ht[(size_t)n * Bsz + t*8] = o;
            #pragma unroll
            for (int m = 1; m < 64; m <<= 1) part += __shfl_xor(part, m, 64);
            if (l == 0) hws[w] = part;
            __syncthreads();
            if (t == 0) hsum[n] = hws[0] + hws[1] + hws[2] + hws[3];
            __syncthreads();
        }
    }
    grid.sync();

    // ================= P3: acc + finish =================
    // block tile 32n x 16d; wave w = b-chunk of 512 (in-block split-K);
    // LDS reduce; fused epilogue out = W + taxa*(acc - hsum*W)/B.
    {
        const int n0 = (bid >> 4) * 32;
        const int d0 = (bid & 15) * 16;

        f32x4 a2[2];
        #pragma unroll
        for (int m = 0; m < 2; ++m) { f32x4 z = {0.f,0.f,0.f,0.f}; a2[m] = z; }

        for (int ks = 0; ks < 16; ++ks) {
            const int bk = w * 512 + ks * 32 + lg * 8;
            bf16x8 am0 = *(const bf16x8*)&Ht[(size_t)(n0 + lr)      * Bsz + bk];
            bf16x8 am1 = *(const bf16x8*)&Ht[(size_t)(n0 + 16 + lr) * Bsz + bk];
            bf16x8 bx  = *(const bf16x8*)&Xt[(size_t)(d0 + lr)      * Bsz + bk];
            a2[0] = __builtin_amdgcn_mfma_f32_16x16x32_bf16(am0, bx, a2[0], 0, 0, 0);
            a2[1] = __builtin_amdgcn_mfma_f32_16x16x32_bf16(am1, bx, a2[1], 0, 0, 0);
        }

        #pragma unroll
        for (int m = 0; m < 2; ++m)
            #pragma unroll
            for (int r = 0; r < 4; ++r)
                red[w][m*16 + lg*4 + r][lr] = a2[m][r];
        __syncthreads();

        float taxa, inv2s2;
        som_params(step, total, &taxa, &inv2s2);
        const float invB = 1.0f / 2048.0f;

        const int nl = t >> 3;          // 0..31
        const int dl = (t & 7) * 2;     // 0,2,..,14
        float s0 = 0.f, s1 = 0.f;
        #pragma unroll
        for (int ww = 0; ww < 4; ++ww) {
            s0 += red[ww][nl][dl];
            s1 += red[ww][nl][dl + 1];
        }
        const int n = n0 + nl;
        const int d = d0 + dl;
        const float hsn = hsum[n];
        const float* wp = &W[(size_t)n * Dd + d];
        float wv0 = wp[0], wv1 = wp[1];
        float2 o = make_float2(wv0 + taxa * (s0 - hsn * wv0) * invB,
                               wv1 + taxa * (s1 - hsn * wv1) * invB);
        *(float2*)&out[(size_t)n * Dd + d] = o;
    }
}

// ---------------------------------------------------------------------------
extern "C" void kernel_launch(void* const* d_in, const int* in_sizes, int n_in,
                              void* d_out, int out_size, void* d_ws, size_t ws_size,
                              hipStream_t stream)
{
    const float* X    = (const float*)d_in[0];
    const float* W    = (const float*)d_in[1];
    const int* step   = (const int*)d_in[3];
    const int* total  = (const int*)d_in[4];
    float* out = (float*)d_out;

    // workspace (~5.07 MB): small | Xt (1 MB) | region A (4 MB).
    // Phase P0/P1 use region A as X/W hi-lo splits (3 MB); P2 overwrites it
    // with Ht (4 MB) after the splits' last use (grid.sync ordering).
    char* p = (char*)d_ws;
    float* w2   = (float*)p;  p += 4096;
    u64*   bmin = (u64*)p;    p += 16384;
    float* hsum = (float*)p;  p += 4096;
    ushort* Xt  = (ushort*)p; p += 1048576;
    char* regA = p;
    ushort* Xhi = (ushort*)regA;
    ushort* Xlo = (ushort*)(regA + 1048576);
    ushort* Whi = (ushort*)(regA + 2097152);
    ushort* Wlo = (ushort*)(regA + 2621440);
    ushort* Ht  = (ushort*)regA;              // 4 MB, aliases splits

    void* args[] = { (void*)&X, (void*)&W, (void*)&step, (void*)&total,
                     (void*)&out, (void*)&w2, (void*)&bmin, (void*)&hsum,
                     (void*)&Xt, (void*)&Xhi, (void*)&Xlo, (void*)&Whi,
                     (void*)&Wlo, (void*)&Ht };
    hipLaunchCooperativeKernel((void*)fused_som, dim3(512), dim3(256),
                               args, 0, stream);
}

// Round 6
// 37.216 us; speedup vs baseline: 6.2302x; 6.2302x over previous
//
#include <hip/hip_runtime.h>
#include <float.h>

#define Bsz 2048
#define Nn  1024
#define Dd  256

typedef __attribute__((ext_vector_type(8))) short bf16x8;
typedef __attribute__((ext_vector_type(4))) float f32x4;
typedef unsigned long long u64;

// round-to-nearest-even f32 -> bf16 bits
__device__ __forceinline__ unsigned short bfr(float x) {
    unsigned u = __float_as_uint(x);
    u += 0x7fffu + ((u >> 16) & 1u);
    return (unsigned short)(u >> 16);
}
__device__ __forceinline__ float bf2f(unsigned short h) {
    return __uint_as_float(((unsigned)h) << 16);
}

__device__ __forceinline__ void som_params(const int* __restrict__ step,
                                           const int* __restrict__ total,
                                           float* taxa, float* inv2s2) {
    float frac = (float)(*step) / (float)(*total);
    float e = __expf(-frac);
    *taxa = 0.5f * e;
    float sigma = 16.0f * e;              // SIGMA_INICIAL = 16
    *inv2s2 = 1.0f / (2.0f * sigma * sigma);
}

// sortable-u32 encoding of f32 (monotone), packed with index; min => argmin
// with first-index (lowest n) tie-break, matching jnp.argmin.
__device__ __forceinline__ u64 packsc(float f, int n) {
    unsigned u = __float_as_uint(f);
    u = (u & 0x80000000u) ? ~u : (u | 0x80000000u);
    return ((u64)u << 32) | (unsigned)n;
}

// ---------------------------------------------------------------------------
// prep (384 blocks): [0,256) W hi/lo split + w2; [256,384) X hi/lo split +
// bf16 transpose Xt[d][b] + bmin init.
// ---------------------------------------------------------------------------
__global__ __launch_bounds__(256) void prep_all(
    const float* __restrict__ X, const float* __restrict__ W,
    ushort* __restrict__ Xhi, ushort* __restrict__ Xlo,
    ushort* __restrict__ Whi, ushort* __restrict__ Wlo,
    ushort* __restrict__ Xt, float* __restrict__ w2,
    u64* __restrict__ bmin)
{
    __shared__ float ld[64][65];
    const int t = threadIdx.x;
    const int bid = blockIdx.x;

    if (bid < 256) {
        // W: 4 rows/block, one wave per row
        int row  = bid * 4 + (t >> 6);
        int lane = t & 63;
        float4 v = ((const float4*)(W + (size_t)row * Dd))[lane];
        float s = v.x*v.x + v.y*v.y + v.z*v.z + v.w*v.w;
        #pragma unroll
        for (int m = 32; m; m >>= 1) s += __shfl_xor(s, m, 64);
        if (lane == 0) w2[row] = s;
        ushort4 h4, l4;
        h4.x = bfr(v.x); l4.x = bfr(v.x - bf2f(h4.x));
        h4.y = bfr(v.y); l4.y = bfr(v.y - bf2f(h4.y));
        h4.z = bfr(v.z); l4.z = bfr(v.z - bf2f(h4.z));
        h4.w = bfr(v.w); l4.w = bfr(v.w - bf2f(h4.w));
        *(ushort4*)&Whi[(size_t)row * Dd + lane * 4] = h4;
        *(ushort4*)&Wlo[(size_t)row * Dd + lane * 4] = l4;
    } else {
        // X: 64b x 64d tile split + transpose
        const int idx = bid - 256;
        const int b0 = (idx & 31) * 64;
        const int d0 = (idx >> 5) * 64;

        if ((idx >> 5) == 0 && t < 64) bmin[b0 + t] = ~0ull;

        #pragma unroll
        for (int p = 0; p < 4; ++p) {
            int flat = p * 256 + t;
            int row = flat >> 4, c4 = flat & 15;
            float4 v = *(const float4*)&X[(size_t)(b0 + row) * Dd + d0 + c4 * 4];
            ushort4 h4, l4;
            h4.x = bfr(v.x); l4.x = bfr(v.x - bf2f(h4.x));
            h4.y = bfr(v.y); l4.y = bfr(v.y - bf2f(h4.y));
            h4.z = bfr(v.z); l4.z = bfr(v.z - bf2f(h4.z));
            h4.w = bfr(v.w); l4.w = bfr(v.w - bf2f(h4.w));
            size_t off = (size_t)(b0 + row) * Dd + d0 + c4 * 4;
            *(ushort4*)&Xhi[off] = h4;
            *(ushort4*)&Xlo[off] = l4;
            ld[row][c4*4+0] = v.x; ld[row][c4*4+1] = v.y;
            ld[row][c4*4+2] = v.z; ld[row][c4*4+3] = v.w;
        }
        __syncthreads();
        #pragma unroll
        for (int q = 0; q < 2; ++q) {
            int idx2 = q * 256 + t;
            int d  = idx2 >> 3;
            int bs = (idx2 & 7) * 8;
            bf16x8 o;
            #pragma unroll
            for (int j = 0; j < 8; ++j) o[j] = (short)bfr(ld[bs + j][d]);
            *(bf16x8*)&Xt[(size_t)(d0 + d) * Bsz + b0 + bs] = o;
        }
    }
}

// ---------------------------------------------------------------------------
// BMU: score[b][n] = w2[n] - 2*dot(X[b],W[n]) via hi/lo-split MFMA;
// packed atomicMin(u64) -> bmin[b].  grid (16 b-tiles of 128, 16 n-tiles of 64)
// 4 waves: wm=b-half, wn=n-half; wave tile 64b x 32n
// ---------------------------------------------------------------------------
__global__ __launch_bounds__(256) void bmu_mfma(
    const ushort* __restrict__ Xhi, const ushort* __restrict__ Xlo,
    const ushort* __restrict__ Whi, const ushort* __restrict__ Wlo,
    const float* __restrict__ w2, u64* __restrict__ bmin)
{
    const int t = threadIdx.x, w = t >> 6, l = t & 63;
    const int wm = w & 1, wn = w >> 1;
    const int b0 = blockIdx.x * 128 + wm * 64;
    const int n0 = blockIdx.y * 64 + wn * 32;
    const int lr = l & 15, lg = l >> 4;

    f32x4 acc[4][2];
    #pragma unroll
    for (int m = 0; m < 4; ++m)
        #pragma unroll
        for (int n = 0; n < 2; ++n) { f32x4 z = {0.f,0.f,0.f,0.f}; acc[m][n] = z; }

    #pragma unroll
    for (int kd = 0; kd < Dd; kd += 32) {
        bf16x8 ah[4], al[4], bh[2], bl[2];
        #pragma unroll
        for (int m = 0; m < 4; ++m) {
            size_t off = (size_t)(b0 + m*16 + lr) * Dd + kd + lg*8;
            ah[m] = *(const bf16x8*)&Xhi[off];
            al[m] = *(const bf16x8*)&Xlo[off];
        }
        #pragma unroll
        for (int n = 0; n < 2; ++n) {
            size_t off = (size_t)(n0 + n*16 + lr) * Dd + kd + lg*8;
            bh[n] = *(const bf16x8*)&Whi[off];
            bl[n] = *(const bf16x8*)&Wlo[off];
        }
        #pragma unroll
        for (int m = 0; m < 4; ++m)
            #pragma unroll
            for (int n = 0; n < 2; ++n) {
                acc[m][n] = __builtin_amdgcn_mfma_f32_16x16x32_bf16(ah[m], bh[n], acc[m][n], 0, 0, 0);
                acc[m][n] = __builtin_amdgcn_mfma_f32_16x16x32_bf16(ah[m], bl[n], acc[m][n], 0, 0, 0);
                acc[m][n] = __builtin_amdgcn_mfma_f32_16x16x32_bf16(al[m], bh[n], acc[m][n], 0, 0, 0);
            }
    }

    float w2v[2]; int nidx[2];
    #pragma unroll
    for (int n = 0; n < 2; ++n) { nidx[n] = n0 + n*16 + lr; w2v[n] = w2[nidx[n]]; }

    #pragma unroll
    for (int m = 0; m < 4; ++m)
        #pragma unroll
        for (int r = 0; r < 4; ++r) {
            u64 p0 = packsc(w2v[0] - 2.f * acc[m][0][r], nidx[0]);
            u64 p1 = packsc(w2v[1] - 2.f * acc[m][1][r], nidx[1]);
            u64 pm = p1 < p0 ? p1 : p0;
            #pragma unroll
            for (int msk = 1; msk < 16; msk <<= 1) {
                unsigned plo = (unsigned)pm, phi = (unsigned)(pm >> 32);
                plo = __shfl_xor(plo, msk, 64);
                phi = __shfl_xor(phi, msk, 64);
                u64 o = ((u64)phi << 32) | plo;
                if (o < pm) pm = o;
            }
            if (lr == 0) {
                int b = b0 + m*16 + lg*4 + r;
                atomicMin(&bmin[b], pm);
            }
        }
}

// ---------------------------------------------------------------------------
// acc + finish with ON-THE-FLY h (no Ht, no hgen kernel):
// out[n][d] = W + taxa*((h@X)[n][d] - hsum[n]*W)/B
// grid (32 n-tiles of 32, 8 d-tiles of 32); 512 thr = 8 waves.
// Wave w: full 32n x 32d tile over b-chunk of 256 (in-block split-K).
// h generated per-lane directly in A-frag layout; hsum reduced exactly
// in-block (covers all 2048 b), deterministic across blocks.
// ---------------------------------------------------------------------------
__global__ __launch_bounds__(512) void acc_finish(
    const ushort* __restrict__ Xt, const u64* __restrict__ bmin,
    const float* __restrict__ W, const int* __restrict__ step,
    const int* __restrict__ total, float* __restrict__ out)
{
    __shared__ float red[8][32][36];   // [wave][n][d] +4 pad
    __shared__ float hws[8][32];       // per-wave hsum partials

    const int t = threadIdx.x, w = t >> 6, l = t & 63;
    const int lr = l & 15, lg = l >> 4;
    const int n0 = blockIdx.x * 32;
    const int d0 = blockIdx.y * 32;

    float taxa, inv2s2;
    som_params(step, total, &taxa, &inv2s2);

    // lane's two n rows: n = n0 + m*16 + lr  ->  nx = m*16+lr, ny = n0>>5
    const float fny  = (float)(n0 >> 5);
    const float fnx0 = (float)lr;
    const float fnx1 = (float)(lr + 16);

    f32x4 acc[2][2];
    #pragma unroll
    for (int m = 0; m < 2; ++m)
        #pragma unroll
        for (int nf = 0; nf < 2; ++nf) { f32x4 z = {0.f,0.f,0.f,0.f}; acc[m][nf] = z; }
    float hs0 = 0.f, hs1 = 0.f;

    #pragma unroll
    for (int ks = 0; ks < 8; ++ks) {
        const int bk = w * 256 + ks * 32 + lg * 8;
        bf16x8 am0, am1;
        #pragma unroll
        for (int j = 0; j < 8; ++j) {
            unsigned idx = (unsigned)(bmin[bk + j] & 0xffffffffu);
            float bx = (float)(idx & 31), by = (float)(idx >> 5);
            float dy  = fny - by;
            float dy2 = dy * dy;
            float dx0 = fnx0 - bx, dx1 = fnx1 - bx;
            float h0 = __expf(-(dx0*dx0 + dy2) * inv2s2);
            float h1 = __expf(-(dx1*dx1 + dy2) * inv2s2);
            am0[j] = (short)bfr(h0);
            am1[j] = (short)bfr(h1);
            hs0 += h0; hs1 += h1;
        }
        bf16x8 bx0 = *(const bf16x8*)&Xt[(size_t)(d0 + lr)      * Bsz + bk];
        bf16x8 bx1 = *(const bf16x8*)&Xt[(size_t)(d0 + 16 + lr) * Bsz + bk];
        acc[0][0] = __builtin_amdgcn_mfma_f32_16x16x32_bf16(am0, bx0, acc[0][0], 0, 0, 0);
        acc[0][1] = __builtin_amdgcn_mfma_f32_16x16x32_bf16(am0, bx1, acc[0][1], 0, 0, 0);
        acc[1][0] = __builtin_amdgcn_mfma_f32_16x16x32_bf16(am1, bx0, acc[1][0], 0, 0, 0);
        acc[1][1] = __builtin_amdgcn_mfma_f32_16x16x32_bf16(am1, bx1, acc[1][1], 0, 0, 0);
    }

    // hsum partials: reduce over lg (same n, different b)
    hs0 += __shfl_xor(hs0, 16, 64); hs0 += __shfl_xor(hs0, 32, 64);
    hs1 += __shfl_xor(hs1, 16, 64); hs1 += __shfl_xor(hs1, 32, 64);
    if (l < 16) { hws[w][l] = hs0; hws[w][16 + l] = hs1; }

    // stash per-wave MFMA partials
    #pragma unroll
    for (int m = 0; m < 2; ++m)
        #pragma unroll
        for (int nf = 0; nf < 2; ++nf)
            #pragma unroll
            for (int r = 0; r < 4; ++r)
                red[w][m*16 + lg*4 + r][nf*16 + lr] = acc[m][nf][r];
    __syncthreads();

    // reduce 8 waves + fused epilogue: 512 threads x 2 outputs (float2)
    const float invB = 1.0f / 2048.0f;
    const int nl = t >> 4;          // 0..31
    const int dl = (t & 15) * 2;    // 0,2,..,30
    float s0 = 0.f, s1 = 0.f, hsn = 0.f;
    #pragma unroll
    for (int ww = 0; ww < 8; ++ww) {
        s0  += red[ww][nl][dl];
        s1  += red[ww][nl][dl + 1];
        hsn += hws[ww][nl];
    }
    const int n = n0 + nl;
    const int d = d0 + dl;
    const float* wp = &W[(size_t)n * Dd + d];
    float wv0 = wp[0], wv1 = wp[1];
    float2 o = make_float2(wv0 + taxa * (s0 - hsn * wv0) * invB,
                           wv1 + taxa * (s1 - hsn * wv1) * invB);
    *(float2*)&out[(size_t)n * Dd + d] = o;
}

// ---------------------------------------------------------------------------
extern "C" void kernel_launch(void* const* d_in, const int* in_sizes, int n_in,
                              void* d_out, int out_size, void* d_ws, size_t ws_size,
                              hipStream_t stream)
{
    const float* X    = (const float*)d_in[0];
    const float* W    = (const float*)d_in[1];
    const int* step   = (const int*)d_in[3];
    const int* total  = (const int*)d_in[4];
    float* out = (float*)d_out;

    // workspace (~4.03 MB)
    char* p = (char*)d_ws;
    float* w2   = (float*)p;  p += 4096;
    u64*   bmin = (u64*)p;    p += 16384;
    ushort* Xt  = (ushort*)p; p += 1048576;
    ushort* Xhi = (ushort*)p; p += 1048576;
    ushort* Xlo = (ushort*)p; p += 1048576;
    ushort* Whi = (ushort*)p; p += 524288;
    ushort* Wlo = (ushort*)p; p += 524288;

    prep_all  <<<384, 256, 0, stream>>>(X, W, Xhi, Xlo, Whi, Wlo, Xt, w2, bmin);
    bmu_mfma  <<<dim3(16, 16), 256, 0, stream>>>(Xhi, Xlo, Whi, Wlo, w2, bmin);
    acc_finish<<<dim3(32, 8), 512, 0, stream>>>(Xt, bmin, W, step, total, out);
}